// Round 21
// baseline (153.979 us; speedup 1.0000x reference)
//
#include <hip/hip_runtime.h>

// ---------------------------------------------------------------------------
// TreeEncoder, round 21 = round 20 with ONE isolated change: s_setprio(1)
// around the MFMA/LDS-read cluster (T5).
//   Mechanism: 8 independent blocks/CU at arbitrary phases (barriers couple
//   only within a block).  Raising priority during the MFMA phase lets
//   compute-phase waves win CU arbitration over other blocks' staging /
//   activation waves.  Guide: +4-7% on phase-diverse structures (attn),
//   ~0% on lockstep GEMM -- ours is phase-diverse across blocks.
//   Everything else byte-identical to r20 (52-54us kernel, VGPR=32,
//   8 blocks/CU, 61% occupancy).
// ---------------------------------------------------------------------------

typedef short bf16x8 __attribute__((ext_vector_type(8)));
typedef float f32x4  __attribute__((ext_vector_type(4)));
typedef float f32x2  __attribute__((ext_vector_type(2)));

#define MFMA16(a, b, c) __builtin_amdgcn_mfma_f32_16x16x32_bf16((a), (b), (c), 0, 0, 0)

#define NEG_L2E (-1.44269504088896f)
#define TWO_L2E (2.88539008177793f)

__device__ __forceinline__ unsigned short f2bf(float f) {
    return (unsigned short)((__float_as_uint(f) + 0x8000u) >> 16);
}
__device__ __forceinline__ float frcp(float x)  { return __builtin_amdgcn_rcpf(x); }
__device__ __forceinline__ float fexp2(float x) { return __builtin_amdgcn_exp2f(x); }

// packed Pade[3/2] merged activation: 2 elements per call.
__device__ __forceinline__ f32x2 act_h2(f32x2 iv, f32x2 ov, f32x2 cv) {
    f32x2 ei = { fexp2(iv.x), fexp2(iv.y) };
    f32x2 eo = { fexp2(ov.x), fexp2(ov.y) };
    f32x2 u  = { fexp2(cv.x), fexp2(cv.y) };
    f32x2 p  = u - 1.0f;
    f32x2 q  = (1.0f + ei) * (u + 1.0f);     // cc = p/q = sig(i)*tanh(c~)
    f32x2 p2 = p * p, q2 = q * q;
    f32x2 t15 = 15.0f * q2;
    f32x2 pn  = p * (t15 + p2);
    f32x2 qd  = (q * (6.0f * p2 + t15)) * (1.0f + eo);
    return pn * f32x2{ frcp(qd.x), frcp(qd.y) };
}

__device__ __forceinline__ bf16x8 pack8(float4 v0, float4 v1) {
    bf16x8 a;
    a[0] = (short)f2bf(v0.x); a[1] = (short)f2bf(v0.y);
    a[2] = (short)f2bf(v0.z); a[3] = (short)f2bf(v0.w);
    a[4] = (short)f2bf(v1.x); a[5] = (short)f2bf(v1.y);
    a[6] = (short)f2bf(v1.z); a[7] = (short)f2bf(v1.w);
    return a;
}

// async global->LDS, 16B/lane; LDS dest = wave-uniform base + lane*16
__device__ __forceinline__ void gload_lds16(const void* gsrc, void* ldst) {
    __builtin_amdgcn_global_load_lds(
        (const __attribute__((address_space(1))) unsigned int*)gsrc,
        (__attribute__((address_space(3))) unsigned int*)ldst, 16, 0, 0);
}

// ---------------------------------------------------------------------------
// Prep (53 blocks x 256): ws layout identical to rounds 8-20.
//   [0,16384) emb frags; [16384,212992) gate frags; [212992,216064) biases.
// ---------------------------------------------------------------------------
__global__ void prep_frags(const float* __restrict__ embW,
                           const float* __restrict__ Wi,
                           const float* __restrict__ Wo,
                           const float* __restrict__ Wc,
                           const float* __restrict__ bWi, const float* __restrict__ bUi,
                           const float* __restrict__ bWo, const float* __restrict__ bUo,
                           const float* __restrict__ bWc, const float* __restrict__ bUc,
                           char* __restrict__ ws) {
    const int tid = threadIdx.x;
    const int fb  = blockIdx.x * 4 + (tid >> 6);
    const int l   = tid & 63;

    if (fb < 208) {
        int g  = l >> 4, c0 = l & 15;
        const float* src;
        int t, kk;
        size_t dst;
        float scale;
        if (fb < 16) {
            t = fb >> 1; kk = fb & 1;
            src = embW;                                   // [64][128]
            dst = (size_t)fb * 1024;
            scale = 1.0f;
        } else {
            int r = fb - 16;                              // (layer*8+t)*12+gate*4+kk
            int layer = r / 96;
            int r2 = r % 96;
            t = r2 / 12;
            int r3 = r2 % 12;
            int gate = r3 >> 2;
            kk = r3 & 3;
            const float* Ws[3] = {Wi, Wo, Wc};
            src = Ws[gate] + (size_t)layer * 128 * 128;   // [128][128]
            dst = 16384 + (size_t)r * 1024;
            scale = (gate == 2) ? TWO_L2E : NEG_L2E;
        }
        bf16x8 v;
#pragma unroll
        for (int e = 0; e < 8; ++e) {
            int k   = kk * 32 + g * 8 + e;
            int col = t * 16 + c0;
            v[e] = (short)f2bf(scale * src[(size_t)k * 128 + col]);
        }
        *reinterpret_cast<bf16x8*>(ws + dst + (size_t)l * 16) = v;
    } else if (blockIdx.x == 52) {
        float* bias = reinterpret_cast<float*>(ws + 212992);
#pragma unroll
        for (int j = 0; j < 3; ++j) {
            int v = j * 256 + tid;              // 0..767
            int layer = v / 384;
            int r = v % 384;
            int gate = r >> 7;
            int c = r & 127;
            int idx = layer * 128 + c;
            float x;
            if (gate == 0)      x = NEG_L2E * (bWi[idx] + bUi[idx]);
            else if (gate == 1) x = NEG_L2E * (bWo[idx] + bUo[idx]);
            else                x = TWO_L2E * (bWc[idx] + bUc[idx]);
            bias[v] = x;
        }
    }
}

// ---------------------------------------------------------------------------
// One step (L = S>>3, T = S&7).  Per step (r20 structure + setprio):
//   setprio(1) -> merged kk-loop (A read once, 3 gates) -> setprio(0) ->
//   barrier -> async-stage S+1 -> packed activation -> barrier.
// ---------------------------------------------------------------------------
template<int S>
__device__ __forceinline__ void t_step(
        char* __restrict__ sbuf,
        const char* __restrict__ frags,
        bf16x8 (&A0)[4], bf16x8 (&A1)[4],
        unsigned short* __restrict__ slab,
        const float* __restrict__ biasf,
        float (* __restrict__ redbuf)[128],
        int w, int l, int g, int c0) {

    constexpr int L = S >> 3;
    constexpr int T = S & 7;
    const int c = T * 16 + c0;
    const float Bi = biasf[L * 384 + c];
    const float Bo = biasf[L * 384 + 128 + c];
    const float Bc = biasf[L * 384 + 256 + c];

    const bf16x8 (&A)[4] = (L == 0) ? A0 : A1;
    const char* sr = sbuf + (size_t)l * 16;

    f32x4 ai = {Bi, Bi, Bi, Bi};
    f32x4 ao = {Bo, Bo, Bo, Bo};
    f32x4 ac = {Bc, Bc, Bc, Bc};

    // T5: favor this wave during the MFMA/LDS-read cluster (cross-block
    // arbitration; blocks are phase-independent on the CU).
    __builtin_amdgcn_s_setprio(1);
#pragma unroll
    for (int kk = 0; kk < 4; ++kk) {
        bf16x8 a  = A[kk];
        bf16x8 bc = *reinterpret_cast<const bf16x8*>(sr + (size_t)(8 + kk) * 1024);
        bf16x8 bi = *reinterpret_cast<const bf16x8*>(sr + (size_t)(0 + kk) * 1024);
        bf16x8 bo = *reinterpret_cast<const bf16x8*>(sr + (size_t)(4 + kk) * 1024);
        ac = MFMA16(a, bc, ac);
        ai = MFMA16(a, bi, ai);
        ao = MFMA16(a, bo, ao);
    }
    __builtin_amdgcn_s_setprio(0);

    __syncthreads();                 // all waves done reading sbuf for step S

    if (S < 15) {                    // async-stage step S+1 (no VGPRs)
        const char* gs = frags + 16384 + (size_t)(S + 1) * 12288;
#pragma unroll
        for (int i = 0; i < 3; ++i)
            gload_lds16(gs + (size_t)(i * 4096 + w * 1024) + (size_t)l * 16,
                        sbuf + i * 4096 + w * 1024);
    }

    // packed activation — covers the staging latency
    f32x2 h01 = act_h2(f32x2{ai[0], ai[1]}, f32x2{ao[0], ao[1]}, f32x2{ac[0], ac[1]});
    f32x2 h23 = act_h2(f32x2{ai[2], ai[3]}, f32x2{ao[2], ao[3]}, f32x2{ac[2], ac[3]});
    if constexpr (L == 1) {
        float hsum = (h01.x + h01.y) + (h23.x + h23.y);
        hsum += __shfl_xor(hsum, 16);
        hsum += __shfl_xor(hsum, 32);
        if (g == 0) redbuf[w][c] = hsum;   // distinct cols per step: no clash
    } else {
        slab[(g * 4 + 0) * 40 + (T & 1) * 16 + c0] = f2bf(h01.x);
        slab[(g * 4 + 1) * 40 + (T & 1) * 16 + c0] = f2bf(h01.y);
        slab[(g * 4 + 2) * 40 + (T & 1) * 16 + c0] = f2bf(h23.x);
        slab[(g * 4 + 3) * 40 + (T & 1) * 16 + c0] = f2bf(h23.y);
        if constexpr ((T & 1) == 1)   // pair complete -> A1 frag (wave-private DS)
            A1[T >> 1] = *reinterpret_cast<const bf16x8*>(&slab[c0 * 40 + g * 8]);
    }

    if (S < 15) __syncthreads();     // staged sbuf visible for step S+1
}

// ---------------------------------------------------------------------------
// Main kernel: 2048 blocks x 256 threads; 16 rows/wave; 8 blocks/CU.
// ---------------------------------------------------------------------------
__global__ __launch_bounds__(256, 8) void tree_enc(
        const float* __restrict__ X,       // [131072][64]
        const float* __restrict__ emb_b,   // [128]
        const char*  __restrict__ frags,   // ws
        float* __restrict__ out) {         // [256][128]

    __shared__ __align__(16) char sbuf[12288];                 // 12288 B
    __shared__ __align__(16) unsigned short slabs[4][16 * 40]; //  5120 B
    __shared__ float redbuf[4][128];                           //  2048 B

    const int tid = threadIdx.x;
    const int w   = tid >> 6;
    const int l   = tid & 63;
    const int g   = l >> 4;
    const int c0  = l & 15;
    const int rowbase = blockIdx.x * 64 + w * 16;
    const int batch   = blockIdx.x >> 3;        // 8 blocks per batch

    unsigned short* __restrict__ slab = slabs[w];
    const float* biasf = reinterpret_cast<const float*>(frags + 212992);

    // -------- async-stage step 0 weights (overlaps the whole embedding) ----
    {
        const char* gs = frags + 16384;
#pragma unroll
        for (int i = 0; i < 3; ++i)
            gload_lds16(gs + (size_t)(i * 4096 + w * 1024) + (size_t)l * 16,
                        sbuf + i * 4096 + w * 1024);
    }

    // -------- embedding: h0 for this wave's 16 rows -> slab -> A0 ----------
    bf16x8 A0[4], A1[4];
    {
        bf16x8 afr0, afr1;
        {
            const float* xr = X + (size_t)(rowbase + c0) * 64;
            float4 v0 = *reinterpret_cast<const float4*>(xr + g * 8);
            float4 v1 = *reinterpret_cast<const float4*>(xr + g * 8 + 4);
            float4 v2 = *reinterpret_cast<const float4*>(xr + 32 + g * 8);
            float4 v3 = *reinterpret_cast<const float4*>(xr + 32 + g * 8 + 4);
            afr0 = pack8(v0, v1);
            afr1 = pack8(v2, v3);
        }
#pragma unroll
        for (int t = 0; t < 8; ++t) {
            const char* eb = frags + (size_t)(t * 2) * 1024 + (size_t)l * 16;
            bf16x8 e0 = *reinterpret_cast<const bf16x8*>(eb);
            bf16x8 e1 = *reinterpret_cast<const bf16x8*>(eb + 1024);
            const float be = emb_b[t * 16 + c0];
            f32x4 acc = {be, be, be, be};
            acc = MFMA16(afr0, e0, acc);
            acc = MFMA16(afr1, e1, acc);
#pragma unroll
            for (int r = 0; r < 4; ++r)
                slab[(g * 4 + r) * 40 + (t & 1) * 16 + c0] = f2bf(acc[r]);
            if (t & 1)
                A0[t >> 1] = *reinterpret_cast<const bf16x8*>(&slab[c0 * 40 + g * 8]);
        }
    }
    __syncthreads();   // embedding done AND step-0 staging drained (vmcnt)

    // -------- 16 steps --------
    t_step< 0>(sbuf, frags, A0, A1, slab, biasf, redbuf, w, l, g, c0);
    t_step< 1>(sbuf, frags, A0, A1, slab, biasf, redbuf, w, l, g, c0);
    t_step< 2>(sbuf, frags, A0, A1, slab, biasf, redbuf, w, l, g, c0);
    t_step< 3>(sbuf, frags, A0, A1, slab, biasf, redbuf, w, l, g, c0);
    t_step< 4>(sbuf, frags, A0, A1, slab, biasf, redbuf, w, l, g, c0);
    t_step< 5>(sbuf, frags, A0, A1, slab, biasf, redbuf, w, l, g, c0);
    t_step< 6>(sbuf, frags, A0, A1, slab, biasf, redbuf, w, l, g, c0);
    t_step< 7>(sbuf, frags, A0, A1, slab, biasf, redbuf, w, l, g, c0);
    t_step< 8>(sbuf, frags, A0, A1, slab, biasf, redbuf, w, l, g, c0);
    t_step< 9>(sbuf, frags, A0, A1, slab, biasf, redbuf, w, l, g, c0);
    t_step<10>(sbuf, frags, A0, A1, slab, biasf, redbuf, w, l, g, c0);
    t_step<11>(sbuf, frags, A0, A1, slab, biasf, redbuf, w, l, g, c0);
    t_step<12>(sbuf, frags, A0, A1, slab, biasf, redbuf, w, l, g, c0);
    t_step<13>(sbuf, frags, A0, A1, slab, biasf, redbuf, w, l, g, c0);
    t_step<14>(sbuf, frags, A0, A1, slab, biasf, redbuf, w, l, g, c0);
    t_step<15>(sbuf, frags, A0, A1, slab, biasf, redbuf, w, l, g, c0);

    // -------- block reduce + one atomic per column --------
    __syncthreads();
    if (tid < 128) {
        float s = redbuf[0][tid] + redbuf[1][tid] + redbuf[2][tid] + redbuf[3][tid];
        atomicAdd(&out[batch * 128 + tid], s * (1.0f / 512.0f));
    }
}

// ---------------------------------------------------------------------------
extern "C" void kernel_launch(void* const* d_in, const int* in_sizes, int n_in,
                              void* d_out, int out_size, void* d_ws, size_t ws_size,
                              hipStream_t stream) {
    const float* X    = (const float*)d_in[0];
    const float* embW = (const float*)d_in[1];
    const float* embb = (const float*)d_in[2];
    const float* Wi   = (const float*)d_in[3];
    const float* Wo   = (const float*)d_in[4];
    const float* Wc   = (const float*)d_in[5];
    const float* bWi  = (const float*)d_in[6];
    const float* bUi  = (const float*)d_in[7];
    const float* bWo  = (const float*)d_in[8];
    const float* bUo  = (const float*)d_in[9];
    const float* bWc  = (const float*)d_in[10];
    const float* bUc  = (const float*)d_in[11];
    float* out = (float*)d_out;
    char*  ws  = (char*)d_ws;

    hipMemsetAsync(d_out, 0, (size_t)out_size * sizeof(float), stream);
    prep_frags<<<53, 256, 0, stream>>>(embW, Wi, Wo, Wc,
                                       bWi, bUi, bWo, bUo, bWc, bUc, ws);
    tree_enc<<<2048, 256, 0, stream>>>(X, embb, (const char*)ws, out);
}

// Round 22
// 58.707 us; speedup vs baseline: 2.6228x; 2.6228x over previous
//
#include <hip/hip_runtime.h>

// ---------------------------------------------------------------------------
// TreeEncoder, round 22 = REVERT to round 19 verbatim (best measured:
// 58.4us total, ~52us kernel, VGPR=32, 8 blocks/CU, 61% occupancy).
//   r21's s_setprio pair broke the compiler's slab-sinking allocation
//   (FETCH/WRITE exploded to 251/284 MB, kernel 180us) -- reverted.
//   Ledger of isolated experiments on the r16 structure:
//     - barrier 32->16 (r18): neutral (residency 8->5 blk/CU cancels)
//     - packed-f32 activation (r19): VALUBusy 51->41%, wall neutral -> KEEP
//     - merged kk-loop (r20): neutral (already CSE'd)
//     - setprio (r21): catastrophic codegen break -> reverted
//   Structure: 2048 blocks x 256 thr, 16 rows/wave, weights async-staged
//   to LDS via global_load_lds (2 barriers/step), slab transpose,
//   per-step shuffle-reduce, Pade[3/2] packed activation, exp2-prescaled
//   weights+biases, 19.4 KB LDS, launch_bounds(256,8).
// ---------------------------------------------------------------------------

typedef short bf16x8 __attribute__((ext_vector_type(8)));
typedef float f32x4  __attribute__((ext_vector_type(4)));
typedef float f32x2  __attribute__((ext_vector_type(2)));

#define MFMA16(a, b, c) __builtin_amdgcn_mfma_f32_16x16x32_bf16((a), (b), (c), 0, 0, 0)

#define NEG_L2E (-1.44269504088896f)
#define TWO_L2E (2.88539008177793f)

__device__ __forceinline__ unsigned short f2bf(float f) {
    return (unsigned short)((__float_as_uint(f) + 0x8000u) >> 16);
}
__device__ __forceinline__ float frcp(float x)  { return __builtin_amdgcn_rcpf(x); }
__device__ __forceinline__ float fexp2(float x) { return __builtin_amdgcn_exp2f(x); }

// packed Pade[3/2] merged activation: 2 elements per call.
//   exp2/rcp scalar (TRANS pipe), polynomial packed (VOP3P).
__device__ __forceinline__ f32x2 act_h2(f32x2 iv, f32x2 ov, f32x2 cv) {
    f32x2 ei = { fexp2(iv.x), fexp2(iv.y) };
    f32x2 eo = { fexp2(ov.x), fexp2(ov.y) };
    f32x2 u  = { fexp2(cv.x), fexp2(cv.y) };
    f32x2 p  = u - 1.0f;
    f32x2 q  = (1.0f + ei) * (u + 1.0f);     // cc = p/q = sig(i)*tanh(c~)
    f32x2 p2 = p * p, q2 = q * q;
    f32x2 t15 = 15.0f * q2;
    f32x2 pn  = p * (t15 + p2);
    f32x2 qd  = (q * (6.0f * p2 + t15)) * (1.0f + eo);
    return pn * f32x2{ frcp(qd.x), frcp(qd.y) };
}

__device__ __forceinline__ bf16x8 pack8(float4 v0, float4 v1) {
    bf16x8 a;
    a[0] = (short)f2bf(v0.x); a[1] = (short)f2bf(v0.y);
    a[2] = (short)f2bf(v0.z); a[3] = (short)f2bf(v0.w);
    a[4] = (short)f2bf(v1.x); a[5] = (short)f2bf(v1.y);
    a[6] = (short)f2bf(v1.z); a[7] = (short)f2bf(v1.w);
    return a;
}

// async global->LDS, 16B/lane; LDS dest = wave-uniform base + lane*16
__device__ __forceinline__ void gload_lds16(const void* gsrc, void* ldst) {
    __builtin_amdgcn_global_load_lds(
        (const __attribute__((address_space(1))) unsigned int*)gsrc,
        (__attribute__((address_space(3))) unsigned int*)ldst, 16, 0, 0);
}

// ---------------------------------------------------------------------------
// Prep (53 blocks x 256): ws layout identical to rounds 8-21.
//   [0,16384) emb frags; [16384,212992) gate frags; [212992,216064) biases.
// ---------------------------------------------------------------------------
__global__ void prep_frags(const float* __restrict__ embW,
                           const float* __restrict__ Wi,
                           const float* __restrict__ Wo,
                           const float* __restrict__ Wc,
                           const float* __restrict__ bWi, const float* __restrict__ bUi,
                           const float* __restrict__ bWo, const float* __restrict__ bUo,
                           const float* __restrict__ bWc, const float* __restrict__ bUc,
                           char* __restrict__ ws) {
    const int tid = threadIdx.x;
    const int fb  = blockIdx.x * 4 + (tid >> 6);
    const int l   = tid & 63;

    if (fb < 208) {
        int g  = l >> 4, c0 = l & 15;
        const float* src;
        int t, kk;
        size_t dst;
        float scale;
        if (fb < 16) {
            t = fb >> 1; kk = fb & 1;
            src = embW;                                   // [64][128]
            dst = (size_t)fb * 1024;
            scale = 1.0f;
        } else {
            int r = fb - 16;                              // (layer*8+t)*12+gate*4+kk
            int layer = r / 96;
            int r2 = r % 96;
            t = r2 / 12;
            int r3 = r2 % 12;
            int gate = r3 >> 2;
            kk = r3 & 3;
            const float* Ws[3] = {Wi, Wo, Wc};
            src = Ws[gate] + (size_t)layer * 128 * 128;   // [128][128]
            dst = 16384 + (size_t)r * 1024;
            scale = (gate == 2) ? TWO_L2E : NEG_L2E;
        }
        bf16x8 v;
#pragma unroll
        for (int e = 0; e < 8; ++e) {
            int k   = kk * 32 + g * 8 + e;
            int col = t * 16 + c0;
            v[e] = (short)f2bf(scale * src[(size_t)k * 128 + col]);
        }
        *reinterpret_cast<bf16x8*>(ws + dst + (size_t)l * 16) = v;
    } else if (blockIdx.x == 52) {
        float* bias = reinterpret_cast<float*>(ws + 212992);
#pragma unroll
        for (int j = 0; j < 3; ++j) {
            int v = j * 256 + tid;              // 0..767
            int layer = v / 384;
            int r = v % 384;
            int gate = r >> 7;
            int c = r & 127;
            int idx = layer * 128 + c;
            float x;
            if (gate == 0)      x = NEG_L2E * (bWi[idx] + bUi[idx]);
            else if (gate == 1) x = NEG_L2E * (bWo[idx] + bUo[idx]);
            else                x = TWO_L2E * (bWc[idx] + bUc[idx]);
            bias[v] = x;
        }
    }
}

// ---------------------------------------------------------------------------
// One step (L = S>>3, T = S&7).  Per step (r16 structure):
//   per-gate MFMA from sbuf -> barrier -> async-stage S+1 (global_load_lds)
//   -> packed activation (covers stage latency) -> barrier.
// ---------------------------------------------------------------------------
template<int S>
__device__ __forceinline__ void t_step(
        char* __restrict__ sbuf,
        const char* __restrict__ frags,
        bf16x8 (&A0)[4], bf16x8 (&A1)[4],
        unsigned short* __restrict__ slab,
        const float* __restrict__ biasf,
        float (* __restrict__ redbuf)[128],
        int w, int l, int g, int c0) {

    constexpr int L = S >> 3;
    constexpr int T = S & 7;
    const int c = T * 16 + c0;
    const float Bi = biasf[L * 384 + c];
    const float Bo = biasf[L * 384 + 128 + c];
    const float Bc = biasf[L * 384 + 256 + c];

    const bf16x8 (&A)[4] = (L == 0) ? A0 : A1;
    const char* sr = sbuf + (size_t)l * 16;

    f32x4 ai = {Bi, Bi, Bi, Bi};
    f32x4 ao = {Bo, Bo, Bo, Bo};
    f32x4 ac = {Bc, Bc, Bc, Bc};
    // per-gate loops: transient weight regs stay tiny (64-reg rung)
#pragma unroll
    for (int kk = 0; kk < 4; ++kk)
        ac = MFMA16(A[kk], *reinterpret_cast<const bf16x8*>(sr + (size_t)(8 + kk) * 1024), ac);
#pragma unroll
    for (int kk = 0; kk < 4; ++kk)
        ai = MFMA16(A[kk], *reinterpret_cast<const bf16x8*>(sr + (size_t)(0 + kk) * 1024), ai);
#pragma unroll
    for (int kk = 0; kk < 4; ++kk)
        ao = MFMA16(A[kk], *reinterpret_cast<const bf16x8*>(sr + (size_t)(4 + kk) * 1024), ao);

    __syncthreads();                 // all waves done reading sbuf for step S

    if (S < 15) {                    // async-stage step S+1 (no VGPRs)
        const char* gs = frags + 16384 + (size_t)(S + 1) * 12288;
#pragma unroll
        for (int i = 0; i < 3; ++i)
            gload_lds16(gs + (size_t)(i * 4096 + w * 1024) + (size_t)l * 16,
                        sbuf + i * 4096 + w * 1024);
    }

    // packed activation — covers the staging latency
    f32x2 h01 = act_h2(f32x2{ai[0], ai[1]}, f32x2{ao[0], ao[1]}, f32x2{ac[0], ac[1]});
    f32x2 h23 = act_h2(f32x2{ai[2], ai[3]}, f32x2{ao[2], ao[3]}, f32x2{ac[2], ac[3]});
    if constexpr (L == 1) {
        float hsum = (h01.x + h01.y) + (h23.x + h23.y);
        hsum += __shfl_xor(hsum, 16);
        hsum += __shfl_xor(hsum, 32);
        if (g == 0) redbuf[w][c] = hsum;   // distinct cols per step: no clash
    } else {
        slab[(g * 4 + 0) * 40 + (T & 1) * 16 + c0] = f2bf(h01.x);
        slab[(g * 4 + 1) * 40 + (T & 1) * 16 + c0] = f2bf(h01.y);
        slab[(g * 4 + 2) * 40 + (T & 1) * 16 + c0] = f2bf(h23.x);
        slab[(g * 4 + 3) * 40 + (T & 1) * 16 + c0] = f2bf(h23.y);
        if constexpr ((T & 1) == 1)   // pair complete -> A1 frag (wave-private DS)
            A1[T >> 1] = *reinterpret_cast<const bf16x8*>(&slab[c0 * 40 + g * 8]);
    }

    if (S < 15) __syncthreads();     // staged sbuf visible for step S+1
}

// ---------------------------------------------------------------------------
// Main kernel: 2048 blocks x 256 threads; 16 rows/wave; 8 blocks/CU.
// ---------------------------------------------------------------------------
__global__ __launch_bounds__(256, 8) void tree_enc(
        const float* __restrict__ X,       // [131072][64]
        const float* __restrict__ emb_b,   // [128]
        const char*  __restrict__ frags,   // ws
        float* __restrict__ out) {         // [256][128]

    __shared__ __align__(16) char sbuf[12288];                 // 12288 B
    __shared__ __align__(16) unsigned short slabs[4][16 * 40]; //  5120 B
    __shared__ float redbuf[4][128];                           //  2048 B

    const int tid = threadIdx.x;
    const int w   = tid >> 6;
    const int l   = tid & 63;
    const int g   = l >> 4;
    const int c0  = l & 15;
    const int rowbase = blockIdx.x * 64 + w * 16;
    const int batch   = blockIdx.x >> 3;        // 8 blocks per batch

    unsigned short* __restrict__ slab = slabs[w];
    const float* biasf = reinterpret_cast<const float*>(frags + 212992);

    // -------- async-stage step 0 weights (overlaps the whole embedding) ----
    {
        const char* gs = frags + 16384;
#pragma unroll
        for (int i = 0; i < 3; ++i)
            gload_lds16(gs + (size_t)(i * 4096 + w * 1024) + (size_t)l * 16,
                        sbuf + i * 4096 + w * 1024);
    }

    // -------- embedding: h0 for this wave's 16 rows -> slab -> A0 ----------
    bf16x8 A0[4], A1[4];
    {
        bf16x8 afr0, afr1;
        {
            const float* xr = X + (size_t)(rowbase + c0) * 64;
            float4 v0 = *reinterpret_cast<const float4*>(xr + g * 8);
            float4 v1 = *reinterpret_cast<const float4*>(xr + g * 8 + 4);
            float4 v2 = *reinterpret_cast<const float4*>(xr + 32 + g * 8);
            float4 v3 = *reinterpret_cast<const float4*>(xr + 32 + g * 8 + 4);
            afr0 = pack8(v0, v1);
            afr1 = pack8(v2, v3);
        }
#pragma unroll
        for (int t = 0; t < 8; ++t) {
            const char* eb = frags + (size_t)(t * 2) * 1024 + (size_t)l * 16;
            bf16x8 e0 = *reinterpret_cast<const bf16x8*>(eb);
            bf16x8 e1 = *reinterpret_cast<const bf16x8*>(eb + 1024);
            const float be = emb_b[t * 16 + c0];
            f32x4 acc = {be, be, be, be};
            acc = MFMA16(afr0, e0, acc);
            acc = MFMA16(afr1, e1, acc);
#pragma unroll
            for (int r = 0; r < 4; ++r)
                slab[(g * 4 + r) * 40 + (t & 1) * 16 + c0] = f2bf(acc[r]);
            if (t & 1)
                A0[t >> 1] = *reinterpret_cast<const bf16x8*>(&slab[c0 * 40 + g * 8]);
        }
    }
    __syncthreads();   // embedding done AND step-0 staging drained (vmcnt)

    // -------- 16 steps --------
    t_step< 0>(sbuf, frags, A0, A1, slab, biasf, redbuf, w, l, g, c0);
    t_step< 1>(sbuf, frags, A0, A1, slab, biasf, redbuf, w, l, g, c0);
    t_step< 2>(sbuf, frags, A0, A1, slab, biasf, redbuf, w, l, g, c0);
    t_step< 3>(sbuf, frags, A0, A1, slab, biasf, redbuf, w, l, g, c0);
    t_step< 4>(sbuf, frags, A0, A1, slab, biasf, redbuf, w, l, g, c0);
    t_step< 5>(sbuf, frags, A0, A1, slab, biasf, redbuf, w, l, g, c0);
    t_step< 6>(sbuf, frags, A0, A1, slab, biasf, redbuf, w, l, g, c0);
    t_step< 7>(sbuf, frags, A0, A1, slab, biasf, redbuf, w, l, g, c0);
    t_step< 8>(sbuf, frags, A0, A1, slab, biasf, redbuf, w, l, g, c0);
    t_step< 9>(sbuf, frags, A0, A1, slab, biasf, redbuf, w, l, g, c0);
    t_step<10>(sbuf, frags, A0, A1, slab, biasf, redbuf, w, l, g, c0);
    t_step<11>(sbuf, frags, A0, A1, slab, biasf, redbuf, w, l, g, c0);
    t_step<12>(sbuf, frags, A0, A1, slab, biasf, redbuf, w, l, g, c0);
    t_step<13>(sbuf, frags, A0, A1, slab, biasf, redbuf, w, l, g, c0);
    t_step<14>(sbuf, frags, A0, A1, slab, biasf, redbuf, w, l, g, c0);
    t_step<15>(sbuf, frags, A0, A1, slab, biasf, redbuf, w, l, g, c0);

    // -------- block reduce + one atomic per column --------
    __syncthreads();
    if (tid < 128) {
        float s = redbuf[0][tid] + redbuf[1][tid] + redbuf[2][tid] + redbuf[3][tid];
        atomicAdd(&out[batch * 128 + tid], s * (1.0f / 512.0f));
    }
}

// ---------------------------------------------------------------------------
extern "C" void kernel_launch(void* const* d_in, const int* in_sizes, int n_in,
                              void* d_out, int out_size, void* d_ws, size_t ws_size,
                              hipStream_t stream) {
    const float* X    = (const float*)d_in[0];
    const float* embW = (const float*)d_in[1];
    const float* embb = (const float*)d_in[2];
    const float* Wi   = (const float*)d_in[3];
    const float* Wo   = (const float*)d_in[4];
    const float* Wc   = (const float*)d_in[5];
    const float* bWi  = (const float*)d_in[6];
    const float* bUi  = (const float*)d_in[7];
    const float* bWo  = (const float*)d_in[8];
    const float* bUo  = (const float*)d_in[9];
    const float* bWc  = (const float*)d_in[10];
    const float* bUc  = (const float*)d_in[11];
    float* out = (float*)d_out;
    char*  ws  = (char*)d_ws;

    hipMemsetAsync(d_out, 0, (size_t)out_size * sizeof(float), stream);
    prep_frags<<<53, 256, 0, stream>>>(embW, Wi, Wo, Wc,
                                       bWi, bUi, bWo, bUo, bWc, bUc, ws);
    tree_enc<<<2048, 256, 0, stream>>>(X, embb, (const char*)ws, out);
}

// Round 23
// 56.050 us; speedup vs baseline: 2.7472x; 1.0474x over previous
//
#include <hip/hip_runtime.h>

// ---------------------------------------------------------------------------
// TreeEncoder, round 23 = round 22 (= r19 best point, ~54us kernel) with the
// hipMemsetAsync dispatch folded into prep_frags (block 52 zeroes the 128KB
// output alongside the bias computation; stream order still guarantees
// completion before tree_enc's atomics).  Main kernel byte-identical.
//   Ledger (isolated experiments on the r16 structure, best = r19):
//     barrier 32->16: neutral | packed act: KEEP | kk-merge: neutral |
//     setprio: codegen break | this round: -1 dispatch.
// ---------------------------------------------------------------------------

typedef short bf16x8 __attribute__((ext_vector_type(8)));
typedef float f32x4  __attribute__((ext_vector_type(4)));
typedef float f32x2  __attribute__((ext_vector_type(2)));

#define MFMA16(a, b, c) __builtin_amdgcn_mfma_f32_16x16x32_bf16((a), (b), (c), 0, 0, 0)

#define NEG_L2E (-1.44269504088896f)
#define TWO_L2E (2.88539008177793f)

__device__ __forceinline__ unsigned short f2bf(float f) {
    return (unsigned short)((__float_as_uint(f) + 0x8000u) >> 16);
}
__device__ __forceinline__ float frcp(float x)  { return __builtin_amdgcn_rcpf(x); }
__device__ __forceinline__ float fexp2(float x) { return __builtin_amdgcn_exp2f(x); }

// packed Pade[3/2] merged activation: 2 elements per call.
//   exp2/rcp scalar (TRANS pipe), polynomial packed (VOP3P).
__device__ __forceinline__ f32x2 act_h2(f32x2 iv, f32x2 ov, f32x2 cv) {
    f32x2 ei = { fexp2(iv.x), fexp2(iv.y) };
    f32x2 eo = { fexp2(ov.x), fexp2(ov.y) };
    f32x2 u  = { fexp2(cv.x), fexp2(cv.y) };
    f32x2 p  = u - 1.0f;
    f32x2 q  = (1.0f + ei) * (u + 1.0f);     // cc = p/q = sig(i)*tanh(c~)
    f32x2 p2 = p * p, q2 = q * q;
    f32x2 t15 = 15.0f * q2;
    f32x2 pn  = p * (t15 + p2);
    f32x2 qd  = (q * (6.0f * p2 + t15)) * (1.0f + eo);
    return pn * f32x2{ frcp(qd.x), frcp(qd.y) };
}

__device__ __forceinline__ bf16x8 pack8(float4 v0, float4 v1) {
    bf16x8 a;
    a[0] = (short)f2bf(v0.x); a[1] = (short)f2bf(v0.y);
    a[2] = (short)f2bf(v0.z); a[3] = (short)f2bf(v0.w);
    a[4] = (short)f2bf(v1.x); a[5] = (short)f2bf(v1.y);
    a[6] = (short)f2bf(v1.z); a[7] = (short)f2bf(v1.w);
    return a;
}

// async global->LDS, 16B/lane; LDS dest = wave-uniform base + lane*16
__device__ __forceinline__ void gload_lds16(const void* gsrc, void* ldst) {
    __builtin_amdgcn_global_load_lds(
        (const __attribute__((address_space(1))) unsigned int*)gsrc,
        (__attribute__((address_space(3))) unsigned int*)ldst, 16, 0, 0);
}

// ---------------------------------------------------------------------------
// Prep (53 blocks x 256): fragments + biases + output zeroing.
//   [0,16384) emb frags; [16384,212992) gate frags; [212992,216064) biases.
// ---------------------------------------------------------------------------
__global__ void prep_frags(const float* __restrict__ embW,
                           const float* __restrict__ Wi,
                           const float* __restrict__ Wo,
                           const float* __restrict__ Wc,
                           const float* __restrict__ bWi, const float* __restrict__ bUi,
                           const float* __restrict__ bWo, const float* __restrict__ bUo,
                           const float* __restrict__ bWc, const float* __restrict__ bUc,
                           char* __restrict__ ws,
                           float* __restrict__ out) {
    const int tid = threadIdx.x;
    const int fb  = blockIdx.x * 4 + (tid >> 6);
    const int l   = tid & 63;

    if (fb < 208) {
        int g  = l >> 4, c0 = l & 15;
        const float* src;
        int t, kk;
        size_t dst;
        float scale;
        if (fb < 16) {
            t = fb >> 1; kk = fb & 1;
            src = embW;                                   // [64][128]
            dst = (size_t)fb * 1024;
            scale = 1.0f;
        } else {
            int r = fb - 16;                              // (layer*8+t)*12+gate*4+kk
            int layer = r / 96;
            int r2 = r % 96;
            t = r2 / 12;
            int r3 = r2 % 12;
            int gate = r3 >> 2;
            kk = r3 & 3;
            const float* Ws[3] = {Wi, Wo, Wc};
            src = Ws[gate] + (size_t)layer * 128 * 128;   // [128][128]
            dst = 16384 + (size_t)r * 1024;
            scale = (gate == 2) ? TWO_L2E : NEG_L2E;
        }
        bf16x8 v;
#pragma unroll
        for (int e = 0; e < 8; ++e) {
            int k   = kk * 32 + g * 8 + e;
            int col = t * 16 + c0;
            v[e] = (short)f2bf(scale * src[(size_t)k * 128 + col]);
        }
        *reinterpret_cast<bf16x8*>(ws + dst + (size_t)l * 16) = v;
    } else if (blockIdx.x == 52) {
        // combined scaled biases: float[2][3][128]
        float* bias = reinterpret_cast<float*>(ws + 212992);
#pragma unroll
        for (int j = 0; j < 3; ++j) {
            int v = j * 256 + tid;              // 0..767
            int layer = v / 384;
            int r = v % 384;
            int gate = r >> 7;
            int c = r & 127;
            int idx = layer * 128 + c;
            float x;
            if (gate == 0)      x = NEG_L2E * (bWi[idx] + bUi[idx]);
            else if (gate == 1) x = NEG_L2E * (bWo[idx] + bUo[idx]);
            else                x = TWO_L2E * (bWc[idx] + bUc[idx]);
            bias[v] = x;
        }
        // zero the output (replaces the hipMemsetAsync dispatch):
        // 256*128 floats = 32768; 256 threads x 32 float4 stores
        float4 z = {0.f, 0.f, 0.f, 0.f};
        float4* o4 = reinterpret_cast<float4*>(out);
#pragma unroll
        for (int j = 0; j < 32; ++j)
            o4[j * 256 + tid] = z;
    }
}

// ---------------------------------------------------------------------------
// One step (L = S>>3, T = S&7).  Per step (r16 structure):
//   per-gate MFMA from sbuf -> barrier -> async-stage S+1 (global_load_lds)
//   -> packed activation (covers stage latency) -> barrier.
// ---------------------------------------------------------------------------
template<int S>
__device__ __forceinline__ void t_step(
        char* __restrict__ sbuf,
        const char* __restrict__ frags,
        bf16x8 (&A0)[4], bf16x8 (&A1)[4],
        unsigned short* __restrict__ slab,
        const float* __restrict__ biasf,
        float (* __restrict__ redbuf)[128],
        int w, int l, int g, int c0) {

    constexpr int L = S >> 3;
    constexpr int T = S & 7;
    const int c = T * 16 + c0;
    const float Bi = biasf[L * 384 + c];
    const float Bo = biasf[L * 384 + 128 + c];
    const float Bc = biasf[L * 384 + 256 + c];

    const bf16x8 (&A)[4] = (L == 0) ? A0 : A1;
    const char* sr = sbuf + (size_t)l * 16;

    f32x4 ai = {Bi, Bi, Bi, Bi};
    f32x4 ao = {Bo, Bo, Bo, Bo};
    f32x4 ac = {Bc, Bc, Bc, Bc};
    // per-gate loops: transient weight regs stay tiny (64-reg rung)
#pragma unroll
    for (int kk = 0; kk < 4; ++kk)
        ac = MFMA16(A[kk], *reinterpret_cast<const bf16x8*>(sr + (size_t)(8 + kk) * 1024), ac);
#pragma unroll
    for (int kk = 0; kk < 4; ++kk)
        ai = MFMA16(A[kk], *reinterpret_cast<const bf16x8*>(sr + (size_t)(0 + kk) * 1024), ai);
#pragma unroll
    for (int kk = 0; kk < 4; ++kk)
        ao = MFMA16(A[kk], *reinterpret_cast<const bf16x8*>(sr + (size_t)(4 + kk) * 1024), ao);

    __syncthreads();                 // all waves done reading sbuf for step S

    if (S < 15) {                    // async-stage step S+1 (no VGPRs)
        const char* gs = frags + 16384 + (size_t)(S + 1) * 12288;
#pragma unroll
        for (int i = 0; i < 3; ++i)
            gload_lds16(gs + (size_t)(i * 4096 + w * 1024) + (size_t)l * 16,
                        sbuf + i * 4096 + w * 1024);
    }

    // packed activation — covers the staging latency
    f32x2 h01 = act_h2(f32x2{ai[0], ai[1]}, f32x2{ao[0], ao[1]}, f32x2{ac[0], ac[1]});
    f32x2 h23 = act_h2(f32x2{ai[2], ai[3]}, f32x2{ao[2], ao[3]}, f32x2{ac[2], ac[3]});
    if constexpr (L == 1) {
        float hsum = (h01.x + h01.y) + (h23.x + h23.y);
        hsum += __shfl_xor(hsum, 16);
        hsum += __shfl_xor(hsum, 32);
        if (g == 0) redbuf[w][c] = hsum;   // distinct cols per step: no clash
    } else {
        slab[(g * 4 + 0) * 40 + (T & 1) * 16 + c0] = f2bf(h01.x);
        slab[(g * 4 + 1) * 40 + (T & 1) * 16 + c0] = f2bf(h01.y);
        slab[(g * 4 + 2) * 40 + (T & 1) * 16 + c0] = f2bf(h23.x);
        slab[(g * 4 + 3) * 40 + (T & 1) * 16 + c0] = f2bf(h23.y);
        if constexpr ((T & 1) == 1)   // pair complete -> A1 frag (wave-private DS)
            A1[T >> 1] = *reinterpret_cast<const bf16x8*>(&slab[c0 * 40 + g * 8]);
    }

    if (S < 15) __syncthreads();     // staged sbuf visible for step S+1
}

// ---------------------------------------------------------------------------
// Main kernel: 2048 blocks x 256 threads; 16 rows/wave; 8 blocks/CU.
// ---------------------------------------------------------------------------
__global__ __launch_bounds__(256, 8) void tree_enc(
        const float* __restrict__ X,       // [131072][64]
        const float* __restrict__ emb_b,   // [128]
        const char*  __restrict__ frags,   // ws
        float* __restrict__ out) {         // [256][128]

    __shared__ __align__(16) char sbuf[12288];                 // 12288 B
    __shared__ __align__(16) unsigned short slabs[4][16 * 40]; //  5120 B
    __shared__ float redbuf[4][128];                           //  2048 B

    const int tid = threadIdx.x;
    const int w   = tid >> 6;
    const int l   = tid & 63;
    const int g   = l >> 4;
    const int c0  = l & 15;
    const int rowbase = blockIdx.x * 64 + w * 16;
    const int batch   = blockIdx.x >> 3;        // 8 blocks per batch

    unsigned short* __restrict__ slab = slabs[w];
    const float* biasf = reinterpret_cast<const float*>(frags + 212992);

    // -------- async-stage step 0 weights (overlaps the whole embedding) ----
    {
        const char* gs = frags + 16384;
#pragma unroll
        for (int i = 0; i < 3; ++i)
            gload_lds16(gs + (size_t)(i * 4096 + w * 1024) + (size_t)l * 16,
                        sbuf + i * 4096 + w * 1024);
    }

    // -------- embedding: h0 for this wave's 16 rows -> slab -> A0 ----------
    bf16x8 A0[4], A1[4];
    {
        bf16x8 afr0, afr1;
        {
            const float* xr = X + (size_t)(rowbase + c0) * 64;
            float4 v0 = *reinterpret_cast<const float4*>(xr + g * 8);
            float4 v1 = *reinterpret_cast<const float4*>(xr + g * 8 + 4);
            float4 v2 = *reinterpret_cast<const float4*>(xr + 32 + g * 8);
            float4 v3 = *reinterpret_cast<const float4*>(xr + 32 + g * 8 + 4);
            afr0 = pack8(v0, v1);
            afr1 = pack8(v2, v3);
        }
#pragma unroll
        for (int t = 0; t < 8; ++t) {
            const char* eb = frags + (size_t)(t * 2) * 1024 + (size_t)l * 16;
            bf16x8 e0 = *reinterpret_cast<const bf16x8*>(eb);
            bf16x8 e1 = *reinterpret_cast<const bf16x8*>(eb + 1024);
            const float be = emb_b[t * 16 + c0];
            f32x4 acc = {be, be, be, be};
            acc = MFMA16(afr0, e0, acc);
            acc = MFMA16(afr1, e1, acc);
#pragma unroll
            for (int r = 0; r < 4; ++r)
                slab[(g * 4 + r) * 40 + (t & 1) * 16 + c0] = f2bf(acc[r]);
            if (t & 1)
                A0[t >> 1] = *reinterpret_cast<const bf16x8*>(&slab[c0 * 40 + g * 8]);
        }
    }
    __syncthreads();   // embedding done AND step-0 staging drained (vmcnt)

    // -------- 16 steps --------
    t_step< 0>(sbuf, frags, A0, A1, slab, biasf, redbuf, w, l, g, c0);
    t_step< 1>(sbuf, frags, A0, A1, slab, biasf, redbuf, w, l, g, c0);
    t_step< 2>(sbuf, frags, A0, A1, slab, biasf, redbuf, w, l, g, c0);
    t_step< 3>(sbuf, frags, A0, A1, slab, biasf, redbuf, w, l, g, c0);
    t_step< 4>(sbuf, frags, A0, A1, slab, biasf, redbuf, w, l, g, c0);
    t_step< 5>(sbuf, frags, A0, A1, slab, biasf, redbuf, w, l, g, c0);
    t_step< 6>(sbuf, frags, A0, A1, slab, biasf, redbuf, w, l, g, c0);
    t_step< 7>(sbuf, frags, A0, A1, slab, biasf, redbuf, w, l, g, c0);
    t_step< 8>(sbuf, frags, A0, A1, slab, biasf, redbuf, w, l, g, c0);
    t_step< 9>(sbuf, frags, A0, A1, slab, biasf, redbuf, w, l, g, c0);
    t_step<10>(sbuf, frags, A0, A1, slab, biasf, redbuf, w, l, g, c0);
    t_step<11>(sbuf, frags, A0, A1, slab, biasf, redbuf, w, l, g, c0);
    t_step<12>(sbuf, frags, A0, A1, slab, biasf, redbuf, w, l, g, c0);
    t_step<13>(sbuf, frags, A0, A1, slab, biasf, redbuf, w, l, g, c0);
    t_step<14>(sbuf, frags, A0, A1, slab, biasf, redbuf, w, l, g, c0);
    t_step<15>(sbuf, frags, A0, A1, slab, biasf, redbuf, w, l, g, c0);

    // -------- block reduce + one atomic per column --------
    __syncthreads();
    if (tid < 128) {
        float s = redbuf[0][tid] + redbuf[1][tid] + redbuf[2][tid] + redbuf[3][tid];
        atomicAdd(&out[batch * 128 + tid], s * (1.0f / 512.0f));
    }
}

// ---------------------------------------------------------------------------
extern "C" void kernel_launch(void* const* d_in, const int* in_sizes, int n_in,
                              void* d_out, int out_size, void* d_ws, size_t ws_size,
                              hipStream_t stream) {
    const float* X    = (const float*)d_in[0];
    const float* embW = (const float*)d_in[1];
    const float* embb = (const float*)d_in[2];
    const float* Wi   = (const float*)d_in[3];
    const float* Wo   = (const float*)d_in[4];
    const float* Wc   = (const float*)d_in[5];
    const float* bWi  = (const float*)d_in[6];
    const float* bUi  = (const float*)d_in[7];
    const float* bWo  = (const float*)d_in[8];
    const float* bUo  = (const float*)d_in[9];
    const float* bWc  = (const float*)d_in[10];
    const float* bUc  = (const float*)d_in[11];
    float* out = (float*)d_out;
    char*  ws  = (char*)d_ws;

    prep_frags<<<53, 256, 0, stream>>>(embW, Wi, Wo, Wc,
                                       bWi, bUi, bWo, bUo, bWc, bUc, ws, out);
    tree_enc<<<2048, 256, 0, stream>>>(X, embb, (const char*)ws, out);
}